// Round 10
// baseline (1745.309 us; speedup 1.0000x reference)
//
#include <hip/hip_runtime.h>
#include <hip/hip_bf16.h>

// ButterFlyNet2D forward — round 10: fused layers 1..5 + FT in ONE kernel,
// 1024 blocks (4 blocks/CU guaranteed co-resident via __launch_bounds__(256,4)),
// software grid barrier. Weight permute folded into k_layer0.
// Intermediate layout: [B][group][y][x][16 ic] bf16, "group" = NEXT layer's
// group index (butterfly permute folded into store).
// d_ws: buf0 (33.5MB) | buf1 (33.5MB) | wbf (11.2MB) | barrier counter.

typedef __attribute__((ext_vector_type(4))) float f32x4;
typedef __attribute__((ext_vector_type(8))) short s16x8;

__device__ __forceinline__ short f2bf(float f) {
  union { float f; unsigned u; } v; v.f = f;
  unsigned r = v.u + 0x7fff + ((v.u >> 16) & 1);   // RNE
  return (short)(r >> 16);
}
__device__ __forceinline__ float bf2f(short s) {
  union { unsigned u; float f; } v; v.u = ((unsigned)(unsigned short)s) << 16;
  return v.f;
}
constexpr int ilog2c(int v) { return v <= 1 ? 0 : 1 + ilog2c(v / 2); }

#define WOFF1 0
#define WOFF2 16384
#define WOFF3 81920
#define WOFF4 344064
#define WOFF5 1392640
#define WTOT  5586944
#define NBLK  1024

// Software grid barrier: one atomic arrival per block, agent-scope fences.
__device__ __forceinline__ void gridbar(unsigned* bar, unsigned target) {
  __threadfence();            // release
  __syncthreads();
  if (threadIdx.x == 0) {
    atomicAdd(bar, 1u);
    while (__hip_atomic_load(bar, __ATOMIC_RELAXED, __HIP_MEMORY_SCOPE_AGENT) < target)
      __builtin_amdgcn_s_sleep(8);
  }
  __syncthreads();
  __threadfence();            // acquire
}

// ---------------- Layer 0 + weight permute (grid-stride over 1024 blocks) ----------------
__global__ __launch_bounds__(256) void k_layer0(
    const float* __restrict__ x, const float* __restrict__ W0,
    const float* __restrict__ b0, short* __restrict__ out,
    const float* __restrict__ W1, const float* __restrict__ W2,
    const float* __restrict__ W3, const float* __restrict__ W4,
    const float* __restrict__ W5, short* __restrict__ wbf,
    unsigned* __restrict__ bar) {
  const int bid = blockIdx.y * 256 + blockIdx.x;
  if (bid == 0 && threadIdx.x == 0) *bar = 0u;
  // ---- weight permute+convert: fp32 -> bf16 A-frag order ----
  for (int idx = bid * 256 + threadIdx.x; idx < WTOT; idx += NBLK * 256) {
    const float* src;
    int local;
    if (idx < WOFF2)      { src = W1; local = idx; }
    else if (idx < WOFF3) { src = W2; local = idx - WOFF2; }
    else if (idx < WOFF4) { src = W3; local = idx - WOFF3; }
    else if (idx < WOFF5) { src = W4; local = idx - WOFF4; }
    else                  { src = W5; local = idx - WOFF5; }
    const int gi = local >> 12, i = local & 4095;
    const int j = i & 7, row = (i >> 3) & 15, g = (i >> 7) & 3, dy = (i >> 9) & 1, t = i >> 10;
    const int k = 8 * g + j, ic = k & 15, dx = k >> 4;
    wbf[idx] = f2bf(src[(size_t)gi * 4096 + ((t * 16 + row) * 16 + ic) * 4 + dy * 2 + dx]);
  }
  // ---- layer 0 conv ----
  constexpr int GS = 4112;
  __shared__ __align__(16) float xs[17 * 64];
  __shared__ __align__(16) short os[4 * GS];
  const int b = blockIdx.x, p0 = blockIdx.y * 8;
  const float* xb = x + (size_t)b * 4096;
  for (int i = threadIdx.x; i < 17 * 16; i += 256) {
    int lr = i >> 4, c4 = i & 15;
    ((float4*)xs)[i] = *(const float4*)(xb + ((2 * p0 + lr) & 63) * 64 + c4 * 4);
  }
  __syncthreads();
  const int oc = threadIdx.x & 63, wv = threadIdx.x >> 6;
  const int g = oc >> 4, c = oc & 15;
  float wp[2][2], wm[2][2];
#pragma unroll
  for (int kh = 0; kh < 2; ++kh)
#pragma unroll
    for (int kw = 0; kw < 2; ++kw) {
      wp[kh][kw] = W0[((oc * 4 + 0) * 2 + kh) * 2 + kw];
      wm[kh][kw] = W0[((oc * 4 + 1) * 2 + kh) * 2 + kw];
    }
  const float bias = b0[oc];
  for (int t = wv; t < 64; t += 4) {
    const int phl = t >> 3, c0 = (t & 7) * 8;
    const int lrA = 2 * phl;
    float vA[9], vB[9], vC[9];
#pragma unroll
    for (int j = 0; j < 8; ++j) {
      vA[j] = xs[lrA * 64 + c0 + j];
      vB[j] = xs[(lrA + 1) * 64 + c0 + j];
      vC[j] = xs[(lrA + 2) * 64 + c0 + j];
    }
    vA[8] = xs[lrA * 64 + ((c0 + 8) & 63)];
    vB[8] = xs[(lrA + 1) * 64 + ((c0 + 8) & 63)];
    vC[8] = xs[(lrA + 2) * 64 + ((c0 + 8) & 63)];
    float pA[9], mA[9], pB[9], mB[9], pC[9], mC[9];
#pragma unroll
    for (int j = 0; j < 9; ++j) {
      pA[j] = fmaxf(vA[j], 0.f); mA[j] = pA[j] - vA[j];
      pB[j] = fmaxf(vB[j], 0.f); mB[j] = pB[j] - vB[j];
      pC[j] = fmaxf(vC[j], 0.f); mC[j] = pC[j] - vC[j];
    }
    float sc0[8], sc1[8];
#pragma unroll
    for (int q = 0; q < 8; ++q) {
      sc0[q] = bias + wp[0][0] * pA[q] + wm[0][0] * mA[q] + wp[0][1] * pA[q + 1] + wm[0][1] * mA[q + 1]
                    + wp[1][0] * pB[q] + wm[1][0] * mB[q] + wp[1][1] * pB[q + 1] + wm[1][1] * mB[q + 1];
      sc1[q] = bias + wp[0][0] * pB[q] + wm[0][0] * mB[q] + wp[0][1] * pB[q + 1] + wm[0][1] * mB[q + 1]
                    + wp[1][0] * pC[q] + wm[1][0] * mC[q] + wp[1][1] * pC[q + 1] + wm[1][1] * mC[q + 1];
    }
#pragma unroll
    for (int p = 0; p < 4; ++p) {
      float po = 0.25f * (fmaxf(sc0[2 * p], 0.f) + fmaxf(sc0[2 * p + 1], 0.f) +
                          fmaxf(sc1[2 * p], 0.f) + fmaxf(sc1[2 * p + 1], 0.f));
      os[g * GS + (phl * 32 + c0 / 2 + p) * 16 + c] = f2bf(po);
    }
  }
  __syncthreads();
#pragma unroll
  for (int gg = 0; gg < 4; ++gg) {
    short* dst = out + ((size_t)b * 4 + gg) * 16384 + (size_t)p0 * 512;
    for (int i = threadIdx.x; i < 512; i += 256)
      *(float4*)&dst[i * 8] = *(const float4*)&os[gg * GS + i * 8];
  }
}

// ---------------- One butterfly conv layer (4096 waves x 4 chunks) ----------------
template <int S, int G>
__device__ __forceinline__ void layer_phase(
    const short* __restrict__ yin, const short* __restrict__ wlayer,
    const float* __restrict__ Bv, short* __restrict__ yout, int wave_global) {
  constexpr int NB = G * G;
  constexpr int SO = S / 2;
  constexpr int LOG_SO = ilog2c(SO);
  constexpr int CPG = 16384 / NB;          // chunks per group (>= 16)
  const int lane = threadIdx.x & 63;
  const int lp = lane & 15, g4 = lane >> 4;
  const int dxg = g4 >> 1, ich = g4 & 1;
  const int chunk0 = wave_global * 4;
  const int gi = chunk0 / CPG;
  const int lc0 = chunk0 - gi * CPG;

  const short* wl = wlayer + (size_t)gi * 4096;
  s16x8 af[4][2];
#pragma unroll
  for (int t = 0; t < 4; ++t)
#pragma unroll
    for (int dy = 0; dy < 2; ++dy)
      af[t][dy] = *(const s16x8*)&wl[(((t * 2 + dy) * 4 + g4) * 16 + lp) * 8];
  f32x4 bv[4];
#pragma unroll
  for (int t = 0; t < 4; ++t)
    bv[t] = *(const f32x4*)&Bv[(size_t)gi * 64 + t * 16 + g4 * 4];

  const int A_y = gi / G, A_x = gi - A_y * G;

#pragma unroll 2
  for (int it = 0; it < 4; ++it) {
    const int pg = (lc0 + it) * 16 + lp;
    const int px = pg & (SO - 1);
    const int py = (pg >> LOG_SO) & (SO - 1);
    const int bi = pg >> (2 * LOG_SO);
    const size_t base = ((size_t)bi * NB + gi) * (S * S * 16) + ich * 8;
    s16x8 bf[3][2];
#pragma unroll
    for (int rr = 0; rr < 3; ++rr) {
      const int r = (2 * py + rr) & (S - 1);
#pragma unroll
      for (int cc = 0; cc < 2; ++cc) {
        const int c = (2 * px + dxg + cc) & (S - 1);
        bf[rr][cc] = *(const s16x8*)&yin[base + (size_t)(r * S + c) * 16];
      }
    }
    f32x4 acc[4][4];
#pragma unroll
    for (int t = 0; t < 4; ++t)
#pragma unroll
      for (int ph = 0; ph < 4; ++ph) acc[t][ph] = bv[t];
#pragma unroll
    for (int phy = 0; phy < 2; ++phy)
#pragma unroll
      for (int phx = 0; phx < 2; ++phx) {
        const int ph = phy * 2 + phx;
#pragma unroll
        for (int dy = 0; dy < 2; ++dy) {
          s16x8 frag = bf[phy + dy][phx];
#pragma unroll
          for (int t = 0; t < 4; ++t)
            acc[t][ph] = __builtin_amdgcn_mfma_f32_16x16x32_bf16(af[t][dy], frag, acc[t][ph], 0, 0, 0);
        }
      }
#pragma unroll
    for (int t = 0; t < 4; ++t) {
      short pk[4];
#pragma unroll
      for (int r = 0; r < 4; ++r) {
        float po = 0.25f * (fmaxf(acc[t][0][r], 0.f) + fmaxf(acc[t][1][r], 0.f) +
                            fmaxf(acc[t][2][r], 0.f) + fmaxf(acc[t][3][r], 0.f));
        pk[r] = f2bf(po);
      }
      const int gip = (A_y * 2 + (t >> 1)) * (2 * G) + A_x * 2 + (t & 1);
      size_t dst = (((size_t)bi * (4 * NB) + gip) * (SO * SO) + py * SO + px) * 16 + g4 * 4;
      *(short4*)&yout[dst] = make_short4(pk[0], pk[1], pk[2], pk[3]);
    }
  }
}

// ---------------- Fused mega-kernel: L1..L5 + FT, 1024 blocks ----------------
__global__ __launch_bounds__(256, 4) void k_mega(
    const float* __restrict__ b1, const float* __restrict__ b2,
    const float* __restrict__ b3, const float* __restrict__ b4,
    const float* __restrict__ b5,
    const float* __restrict__ Wft, const float* __restrict__ bft,
    short* __restrict__ buf0, short* __restrict__ buf1,
    const short* __restrict__ wbf, float* __restrict__ out,
    unsigned* __restrict__ bar) {
  const int wave_global = blockIdx.x * 4 + (threadIdx.x >> 6);
  layer_phase<32, 2>(buf0, wbf + WOFF1, b1, buf1, wave_global);  gridbar(bar, NBLK * 1);
  layer_phase<16, 4>(buf1, wbf + WOFF2, b2, buf0, wave_global);  gridbar(bar, NBLK * 2);
  layer_phase<8, 8>(buf0, wbf + WOFF3, b3, buf1, wave_global);   gridbar(bar, NBLK * 3);
  layer_phase<4, 16>(buf1, wbf + WOFF4, b4, buf0, wave_global);  gridbar(bar, NBLK * 4);
  layer_phase<2, 32>(buf0, wbf + WOFF5, b5, buf1, wave_global);  gridbar(bar, NBLK * 5);

  // ---- FT phase: register-resident Wft row, 4 b per thread ----
  {
    const int n = (blockIdx.x & 63) * 64 + (threadIdx.x & 63);
    const int b0i = (blockIdx.x >> 6) * 16 + (threadIdx.x >> 6) * 4;
    float w[64];
    const float4* wp = (const float4*)(Wft + (size_t)n * 64);
#pragma unroll
    for (int j = 0; j < 16; ++j) {
      float4 t = wp[j];
      w[4 * j] = t.x; w[4 * j + 1] = t.y; w[4 * j + 2] = t.z; w[4 * j + 3] = t.w;
    }
    const float4 bq = *(const float4*)(bft + (size_t)n * 4);
#pragma unroll 2
    for (int bb = 0; bb < 4; ++bb) {
      const int b = b0i + bb;
      const short* vp = buf1 + ((size_t)b * 4096 + n) * 16;
      s16x8 a0 = *(const s16x8*)vp;
      s16x8 a1 = *(const s16x8*)(vp + 8);
      float vv[16];
#pragma unroll
      for (int j = 0; j < 8; ++j) { vv[j] = bf2f(a0[j]); vv[8 + j] = bf2f(a1[j]); }
      float f0 = bq.x, f1 = bq.y, f2 = bq.z, f3 = bq.w;
#pragma unroll
      for (int j = 0; j < 16; ++j) {
        f0 += vv[j] * w[j];
        f1 += vv[j] * w[16 + j];
        f2 += vv[j] * w[32 + j];
        f3 += vv[j] * w[48 + j];
      }
      out[(size_t)b * 8192 + n] = f0 - f1;
      out[(size_t)b * 8192 + 4096 + n] = f2 - f3;
    }
  }
}

extern "C" void kernel_launch(void* const* d_in, const int* in_sizes, int n_in,
                              void* d_out, int out_size, void* d_ws, size_t ws_size,
                              hipStream_t stream) {
  const float* x   = (const float*)d_in[0];
  const float* W0  = (const float*)d_in[1];
  const float* b0  = (const float*)d_in[2];
  const float* Wft = (const float*)d_in[3];
  const float* bft = (const float*)d_in[4];
  const float* W1 = (const float*)d_in[5];  const float* b1 = (const float*)d_in[6];
  const float* W2 = (const float*)d_in[7];  const float* b2 = (const float*)d_in[8];
  const float* W3 = (const float*)d_in[9];  const float* b3 = (const float*)d_in[10];
  const float* W4 = (const float*)d_in[11]; const float* b4 = (const float*)d_in[12];
  const float* W5 = (const float*)d_in[13]; const float* b5 = (const float*)d_in[14];

  short* buf0 = (short*)d_ws;                       // 16.7M bf16 = 33.5 MB
  short* buf1 = buf0 + (size_t)16777216;
  short* wbf  = buf1 + (size_t)16777216;            // 11.2 MB permuted weights
  unsigned* bar = (unsigned*)(wbf + (size_t)((WTOT + 255) & ~255));

  k_layer0<<<dim3(256, 4), 256, 0, stream>>>(x, W0, b0, buf0, W1, W2, W3, W4, W5, wbf, bar);
  k_mega<<<dim3(NBLK), 256, 0, stream>>>(b1, b2, b3, b4, b5, Wft, bft,
                                         buf0, buf1, wbf, (float*)d_out, bar);
}

// Round 11
// 250.463 us; speedup vs baseline: 6.9683x; 6.9683x over previous
//
#include <hip/hip_runtime.h>
#include <hip/hip_bf16.h>

// ButterFlyNet2D forward — round 11: back to split kernels (r7 structure) with
// (1) coalesced k_wconv via LDS permute, (2) bconv ITW=4, (3) XCD block swizzle.
// Intermediate layout: [B][group][y][x][16 ic] bf16, "group" = NEXT layer's
// group index (butterfly permute folded into store).
// d_ws: buf0 (33.5MB) | buf1 (33.5MB) | wbf (11.2MB bf16 A-frag-ordered weights).

typedef __attribute__((ext_vector_type(4))) float f32x4;
typedef __attribute__((ext_vector_type(8))) short s16x8;

__device__ __forceinline__ short f2bf(float f) {
  union { float f; unsigned u; } v; v.f = f;
  unsigned r = v.u + 0x7fff + ((v.u >> 16) & 1);   // RNE
  return (short)(r >> 16);
}
__device__ __forceinline__ float bf2f(short s) {
  union { unsigned u; float f; } v; v.u = ((unsigned)(unsigned short)s) << 16;
  return v.f;
}
constexpr int ilog2c(int v) { return v <= 1 ? 0 : 1 + ilog2c(v / 2); }

#define WOFF1 0
#define WOFF2 16384
#define WOFF3 81920
#define WOFF4 344064
#define WOFF5 1392640
#define WTOT  5586944

// ---------------- Weight permute: coalesced read -> LDS scatter -> coalesced write ----------------
// 1364 groups total; 4 groups per block (341 blocks exactly).
__global__ __launch_bounds__(256) void k_wconv(
    const float* __restrict__ W1, const float* __restrict__ W2,
    const float* __restrict__ W3, const float* __restrict__ W4,
    const float* __restrict__ W5, short* __restrict__ wbf) {
  __shared__ short ws[4][4096];
  const int tid = threadIdx.x;
#pragma unroll
  for (int lg = 0; lg < 4; ++lg) {
    const int gg = blockIdx.x * 4 + lg;           // global group id 0..1363
    const float* src;
    int base;
    if (gg < 4)        { src = W1; base = 0; }
    else if (gg < 20)  { src = W2; base = 4; }
    else if (gg < 84)  { src = W3; base = 20; }
    else if (gg < 340) { src = W4; base = 84; }
    else               { src = W5; base = 340; }
    const float* gp = src + (size_t)(gg - base) * 4096;
    // coalesced: thread reads 16 consecutive floats (4x float4)
#pragma unroll
    for (int q = 0; q < 4; ++q) {
      float4 v = *(const float4*)(gp + tid * 16 + q * 4);
      float vv[4] = {v.x, v.y, v.z, v.w};
#pragma unroll
      for (int e = 0; e < 4; ++e) {
        const int s = tid * 16 + q * 4 + e;       // s = oc*64 + ic*4 + dy*2 + dx
        const int oc = s >> 6, ic = (s >> 2) & 15, dy = (s >> 1) & 1, dx = s & 1;
        const int t = oc >> 4, row = oc & 15;
        const int k = dx * 16 + ic, g = k >> 3, j = k & 7;
        ws[lg][(((t * 2 + dy) * 4 + g) * 16 + row) * 8 + j] = f2bf(vv[e]);
      }
    }
  }
  __syncthreads();
  // coalesced write: 4 groups x 4096 shorts = 2048 float4
  short* dst = wbf + (size_t)blockIdx.x * 16384;
  for (int i = tid; i < 2048; i += 256)
    ((float4*)dst)[i] = ((const float4*)&ws[0][0])[i];
}

// ---------------- Layer 0: split -> conv(4->64,2x2) -> relu -> pool ----------------
__global__ __launch_bounds__(256) void k_layer0(
    const float* __restrict__ x, const float* __restrict__ W0,
    const float* __restrict__ b0, short* __restrict__ out) {
  constexpr int GS = 4112;
  __shared__ __align__(16) float xs[17 * 64];
  __shared__ __align__(16) short os[4 * GS];
  const int b = blockIdx.x, p0 = blockIdx.y * 8;
  const float* xb = x + (size_t)b * 4096;
  for (int i = threadIdx.x; i < 17 * 16; i += 256) {
    int lr = i >> 4, c4 = i & 15;
    ((float4*)xs)[i] = *(const float4*)(xb + ((2 * p0 + lr) & 63) * 64 + c4 * 4);
  }
  __syncthreads();
  const int oc = threadIdx.x & 63, wv = threadIdx.x >> 6;
  const int g = oc >> 4, c = oc & 15;
  float wp[2][2], wm[2][2];
#pragma unroll
  for (int kh = 0; kh < 2; ++kh)
#pragma unroll
    for (int kw = 0; kw < 2; ++kw) {
      wp[kh][kw] = W0[((oc * 4 + 0) * 2 + kh) * 2 + kw];
      wm[kh][kw] = W0[((oc * 4 + 1) * 2 + kh) * 2 + kw];
    }
  const float bias = b0[oc];
  for (int t = wv; t < 64; t += 4) {
    const int phl = t >> 3, c0 = (t & 7) * 8;
    const int lrA = 2 * phl;
    float vA[9], vB[9], vC[9];
#pragma unroll
    for (int j = 0; j < 8; ++j) {
      vA[j] = xs[lrA * 64 + c0 + j];
      vB[j] = xs[(lrA + 1) * 64 + c0 + j];
      vC[j] = xs[(lrA + 2) * 64 + c0 + j];
    }
    vA[8] = xs[lrA * 64 + ((c0 + 8) & 63)];
    vB[8] = xs[(lrA + 1) * 64 + ((c0 + 8) & 63)];
    vC[8] = xs[(lrA + 2) * 64 + ((c0 + 8) & 63)];
    float pA[9], mA[9], pB[9], mB[9], pC[9], mC[9];
#pragma unroll
    for (int j = 0; j < 9; ++j) {
      pA[j] = fmaxf(vA[j], 0.f); mA[j] = pA[j] - vA[j];
      pB[j] = fmaxf(vB[j], 0.f); mB[j] = pB[j] - vB[j];
      pC[j] = fmaxf(vC[j], 0.f); mC[j] = pC[j] - vC[j];
    }
    float sc0[8], sc1[8];
#pragma unroll
    for (int q = 0; q < 8; ++q) {
      sc0[q] = bias + wp[0][0] * pA[q] + wm[0][0] * mA[q] + wp[0][1] * pA[q + 1] + wm[0][1] * mA[q + 1]
                    + wp[1][0] * pB[q] + wm[1][0] * mB[q] + wp[1][1] * pB[q + 1] + wm[1][1] * mB[q + 1];
      sc1[q] = bias + wp[0][0] * pB[q] + wm[0][0] * mB[q] + wp[0][1] * pB[q + 1] + wm[0][1] * mB[q + 1]
                    + wp[1][0] * pC[q] + wm[1][0] * mC[q] + wp[1][1] * pC[q + 1] + wm[1][1] * mC[q + 1];
    }
#pragma unroll
    for (int p = 0; p < 4; ++p) {
      float po = 0.25f * (fmaxf(sc0[2 * p], 0.f) + fmaxf(sc0[2 * p + 1], 0.f) +
                          fmaxf(sc1[2 * p], 0.f) + fmaxf(sc1[2 * p + 1], 0.f));
      os[g * GS + (phl * 32 + c0 / 2 + p) * 16 + c] = f2bf(po);
    }
  }
  __syncthreads();
#pragma unroll
  for (int gg = 0; gg < 4; ++gg) {
    short* dst = out + ((size_t)b * 4 + gg) * 16384 + (size_t)p0 * 512;
    for (int i = threadIdx.x; i < 512; i += 256)
      *(float4*)&dst[i * 8] = *(const float4*)&os[gg * GS + i * 8];
  }
}

// ---------------- Direct MFMA recursion layer (no LDS, no barriers) ----------------
// 1024 blocks (1D), XCD-swizzled; each wave: 4 chunks of 16 pooled pos x 64 oc.
template <int S, int G>
__global__ __launch_bounds__(256) void k_bconv(
    const short* __restrict__ yin, const short* __restrict__ wbf,
    const float* __restrict__ Bv, short* __restrict__ yout) {
  constexpr int NB = G * G;
  constexpr int SO = S / 2;
  constexpr int LOG_SO = ilog2c(SO);
  constexpr int CPG = 16384 / NB;          // chunks per group (>= 16, multiple of 4)
  constexpr int ITW = 4;
  // XCD swizzle: hw-block f -> data-block swz; XCD(f)=f%8 gets contiguous slice
  const int swz = (blockIdx.x & 7) * 128 + (blockIdx.x >> 3);
  const int lane = threadIdx.x & 63, wv = threadIdx.x >> 6;
  const int lp = lane & 15, g4 = lane >> 4;
  const int dxg = g4 >> 1, ich = g4 & 1;
  const int chunk0 = (swz * 4 + wv) * ITW;
  const int gi = chunk0 / CPG;
  const int lc0 = chunk0 - gi * CPG;

  // A-frags: whole 64x64 weight matrix in 32 VGPR/lane
  const short* wl = wbf + (size_t)gi * 4096;
  s16x8 af[4][2];
#pragma unroll
  for (int t = 0; t < 4; ++t)
#pragma unroll
    for (int dy = 0; dy < 2; ++dy)
      af[t][dy] = *(const s16x8*)&wl[(((t * 2 + dy) * 4 + g4) * 16 + lp) * 8];
  f32x4 bv[4];
#pragma unroll
  for (int t = 0; t < 4; ++t)
    bv[t] = *(const f32x4*)&Bv[(size_t)gi * 64 + t * 16 + g4 * 4];

  const int A_y = gi / G, A_x = gi - A_y * G;

#pragma unroll 2
  for (int it = 0; it < ITW; ++it) {
    const int pg = (lc0 + it) * 16 + lp;
    const int px = pg & (SO - 1);
    const int py = (pg >> LOG_SO) & (SO - 1);
    const int bi = pg >> (2 * LOG_SO);
    const size_t base = ((size_t)bi * NB + gi) * (S * S * 16) + ich * 8;
    s16x8 bf[3][2];
#pragma unroll
    for (int rr = 0; rr < 3; ++rr) {
      const int r = (2 * py + rr) & (S - 1);
#pragma unroll
      for (int cc = 0; cc < 2; ++cc) {
        const int c = (2 * px + dxg + cc) & (S - 1);
        bf[rr][cc] = *(const s16x8*)&yin[base + (size_t)(r * S + c) * 16];
      }
    }
    f32x4 acc[4][4];
#pragma unroll
    for (int t = 0; t < 4; ++t)
#pragma unroll
      for (int ph = 0; ph < 4; ++ph) acc[t][ph] = bv[t];
#pragma unroll
    for (int phy = 0; phy < 2; ++phy)
#pragma unroll
      for (int phx = 0; phx < 2; ++phx) {
        const int ph = phy * 2 + phx;
#pragma unroll
        for (int dy = 0; dy < 2; ++dy) {
          s16x8 frag = bf[phy + dy][phx];
#pragma unroll
          for (int t = 0; t < 4; ++t)
            acc[t][ph] = __builtin_amdgcn_mfma_f32_16x16x32_bf16(af[t][dy], frag, acc[t][ph], 0, 0, 0);
        }
      }
#pragma unroll
    for (int t = 0; t < 4; ++t) {
      short pk[4];
#pragma unroll
      for (int r = 0; r < 4; ++r) {
        float po = 0.25f * (fmaxf(acc[t][0][r], 0.f) + fmaxf(acc[t][1][r], 0.f) +
                            fmaxf(acc[t][2][r], 0.f) + fmaxf(acc[t][3][r], 0.f));
        pk[r] = f2bf(po);
      }
      const int gip = (A_y * 2 + (t >> 1)) * (2 * G) + A_x * 2 + (t & 1);
      size_t dst = (((size_t)bi * (4 * NB) + gip) * (SO * SO) + py * SO + px) * 16 + g4 * 4;
      *(short4*)&yout[dst] = make_short4(pk[0], pk[1], pk[2], pk[3]);
    }
  }
}

// ---------------- FT layer: register-resident Wft row, 8 b per thread ----------------
__global__ __launch_bounds__(256) void k_ft(
    const short* __restrict__ v, const float* __restrict__ Wft,
    const float* __restrict__ bft, float* __restrict__ out) {
  const int n = blockIdx.x * 64 + (threadIdx.x & 63);
  const int b0 = blockIdx.y * 32 + (threadIdx.x >> 6) * 8;
  float w[64];
  const float4* wp = (const float4*)(Wft + (size_t)n * 64);
#pragma unroll
  for (int j = 0; j < 16; ++j) {
    float4 t = wp[j];
    w[4 * j] = t.x; w[4 * j + 1] = t.y; w[4 * j + 2] = t.z; w[4 * j + 3] = t.w;
  }
  const float4 bq = *(const float4*)(bft + (size_t)n * 4);
#pragma unroll 2
  for (int bb = 0; bb < 8; ++bb) {
    const int b = b0 + bb;
    const short* vp = v + ((size_t)b * 4096 + n) * 16;
    s16x8 a0 = *(const s16x8*)vp;
    s16x8 a1 = *(const s16x8*)(vp + 8);
    float vv[16];
#pragma unroll
    for (int j = 0; j < 8; ++j) { vv[j] = bf2f(a0[j]); vv[8 + j] = bf2f(a1[j]); }
    float f0 = bq.x, f1 = bq.y, f2 = bq.z, f3 = bq.w;
#pragma unroll
    for (int j = 0; j < 16; ++j) {
      f0 += vv[j] * w[j];
      f1 += vv[j] * w[16 + j];
      f2 += vv[j] * w[32 + j];
      f3 += vv[j] * w[48 + j];
    }
    out[(size_t)b * 8192 + n] = f0 - f1;
    out[(size_t)b * 8192 + 4096 + n] = f2 - f3;
  }
}

extern "C" void kernel_launch(void* const* d_in, const int* in_sizes, int n_in,
                              void* d_out, int out_size, void* d_ws, size_t ws_size,
                              hipStream_t stream) {
  const float* x   = (const float*)d_in[0];
  const float* W0  = (const float*)d_in[1];
  const float* b0  = (const float*)d_in[2];
  const float* Wft = (const float*)d_in[3];
  const float* bft = (const float*)d_in[4];
  const float* W1 = (const float*)d_in[5];  const float* b1 = (const float*)d_in[6];
  const float* W2 = (const float*)d_in[7];  const float* b2 = (const float*)d_in[8];
  const float* W3 = (const float*)d_in[9];  const float* b3 = (const float*)d_in[10];
  const float* W4 = (const float*)d_in[11]; const float* b4 = (const float*)d_in[12];
  const float* W5 = (const float*)d_in[13]; const float* b5 = (const float*)d_in[14];

  short* buf0 = (short*)d_ws;                       // 16.7M bf16 = 33.5 MB
  short* buf1 = buf0 + (size_t)16777216;
  short* wbf  = buf1 + (size_t)16777216;            // 11.2 MB permuted weights

  k_wconv<<<341, 256, 0, stream>>>(W1, W2, W3, W4, W5, wbf);
  k_layer0<<<dim3(256, 4), 256, 0, stream>>>(x, W0, b0, buf0);
  // 1024 blocks each, XCD-swizzled inside
  k_bconv<32, 2><<<1024, 256, 0, stream>>>(buf0, wbf + WOFF1, b1, buf1);
  k_bconv<16, 4><<<1024, 256, 0, stream>>>(buf1, wbf + WOFF2, b2, buf0);
  k_bconv<8, 8><<<1024, 256, 0, stream>>>(buf0, wbf + WOFF3, b3, buf1);
  k_bconv<4, 16><<<1024, 256, 0, stream>>>(buf1, wbf + WOFF4, b4, buf0);
  k_bconv<2, 32><<<1024, 256, 0, stream>>>(buf0, wbf + WOFF5, b5, buf1);
  k_ft<<<dim3(64, 8), 256, 0, stream>>>(buf1, Wft, bft, (float*)d_out);
}